// Round 7
// baseline (468.952 us; speedup 1.0000x reference)
//
#include <hip/hip_runtime.h>

// ---------------------------------------------------------------------------
// Causal self-attention, B=4 T=2048 D=1024 H=16 HD=64, fp32 in/out.
// cast x->bf16 ; transpose-cast W ; fused QKV GEMM (N=3072) ;
// flash attention (causal, fixed-offset softmax) ; O GEMM.
// MFMA v_mfma_f32_16x16x32_bf16, HW-verified layouts:
//   A/Bt frag: lane reads row (lane&15), k = (lane>>4)*8 .. +7 (16B contig)
//   C/D:       col = lane&15, row = (lane>>4)*4 + reg
// R7: attn = paired 16-row q-tiles (i,127-i) -> uniform 33 chunk-units/wave
// (no occupancy tail); raw v_exp_f32 (exp2f libcall was ~200 VALU/chunk);
// smaller live set (no K prefetch rotation) for 4 waves/SIMD residency.
// ---------------------------------------------------------------------------

#define B_  4
#define T_  2048
#define D_  1024
#define H_  16
#define HD_ 64
#define M_  (B_ * T_)   // 8192 rows

typedef __bf16 bf16x8 __attribute__((ext_vector_type(8)));
typedef float  floatx4 __attribute__((ext_vector_type(4)));

__device__ __forceinline__ unsigned short f2b(float f) {
  unsigned int u = __float_as_uint(f);
  unsigned int r = (u + 0x7fffu + ((u >> 16) & 1u)) >> 16;
  return (unsigned short)r;
}

__device__ __forceinline__ float fast_exp2(float x) {
#if __has_builtin(__builtin_amdgcn_exp2f)
  return __builtin_amdgcn_exp2f(x);   // raw v_exp_f32
#else
  return exp2f(x);
#endif
}

__device__ __forceinline__ void async_ld16(const void* g, void* l) {
  __builtin_amdgcn_global_load_lds(
      (const __attribute__((address_space(1))) void*)g,
      (__attribute__((address_space(3))) void*)l, 16, 0, 0);
}

// --------------------------- prep kernels ----------------------------------

__global__ void cast_fp32_to_bf16(const float* __restrict__ in,
                                  unsigned short* __restrict__ out, int n) {
  int i = (blockIdx.x * 256 + threadIdx.x) * 4;
  if (i >= n) return;
  float4 v = *(const float4*)(in + i);
  ushort4 o;
  o.x = f2b(v.x); o.y = f2b(v.y); o.z = f2b(v.z); o.w = f2b(v.w);
  *(ushort4*)(out + i) = o;
}

__global__ void transpose_cast(const float* __restrict__ W0, const float* __restrict__ W1,
                               const float* __restrict__ W2, const float* __restrict__ W3,
                               unsigned short* __restrict__ O0, unsigned short* __restrict__ O1,
                               unsigned short* __restrict__ O2, unsigned short* __restrict__ O3) {
  __shared__ float tile[32][33];
  int z = blockIdx.z;
  const float* W = z == 0 ? W0 : z == 1 ? W1 : z == 2 ? W2 : W3;
  unsigned short* O = z == 0 ? O0 : z == 1 ? O1 : z == 2 ? O2 : O3;
  int n0 = blockIdx.x * 32, k0 = blockIdx.y * 32;
  int tx = threadIdx.x, ty = threadIdx.y;
#pragma unroll
  for (int i = 0; i < 4; ++i)
    tile[ty + i * 8][tx] = W[(size_t)(k0 + ty + i * 8) * D_ + n0 + tx];
  __syncthreads();
#pragma unroll
  for (int i = 0; i < 4; ++i)
    O[(size_t)(n0 + ty + i * 8) * D_ + k0 + tx] = f2b(tile[tx][ty + i * 8]);
}

// --------------------------- fused QKV GEMM --------------------------------
// A [8192][1024] bf16, Wt [3072][1024] bf16 (Wq^T|Wk^T|Wv^T contiguous).
// Q,K out: bf16 [B][H][T][HD]; V out: bf16 [B][H][HD][Tp] key-permuted.

__global__ __launch_bounds__(256, 2)
void gemm_qkv(const unsigned short* __restrict__ A,
              const unsigned short* __restrict__ Wt,
              const float* __restrict__ bq, const float* __restrict__ bk,
              const float* __restrict__ bv,
              unsigned short* __restrict__ Qo, unsigned short* __restrict__ Ko,
              unsigned short* __restrict__ Vo) {
  __shared__ unsigned short As[128 * 32];
  __shared__ unsigned short Bs[128 * 32];
  const int K = D_;

  const int tid = threadIdx.x;
  const int wave = tid >> 6, lane = tid & 63;
  const int quad = lane >> 4, l16 = lane & 15;
  const int m0 = blockIdx.y * 128, n0 = blockIdx.x * 128;
  const int wm = (wave >> 1) * 64, wn = (wave & 1) * 64;

  const int c0 = wave * 2, c1 = c0 + 1;
  const int r0 = c0 * 16 + (lane >> 2);
  const int r1 = r0 + 16;
  const int kb = (lane & 3) * 8;

  const unsigned short* Ag0 = A + (size_t)(m0 + r0) * K + kb;
  const unsigned short* Ag1 = A + (size_t)(m0 + r1) * K + kb;
  const unsigned short* Bg0 = Wt + (size_t)(n0 + r0) * K + kb;
  const unsigned short* Bg1 = Wt + (size_t)(n0 + r1) * K + kb;

  floatx4 acc[4][4] = {};

  for (int kt = 0; kt < K; kt += 32) {
    async_ld16(Ag0 + kt, &As[c0 * 512]);
    async_ld16(Ag1 + kt, &As[c1 * 512]);
    async_ld16(Bg0 + kt, &Bs[c0 * 512]);
    async_ld16(Bg1 + kt, &Bs[c1 * 512]);
    __syncthreads();

    bf16x8 a[4], b[4];
#pragma unroll
    for (int i = 0; i < 4; ++i)
      a[i] = *(const bf16x8*)&As[(wm + i * 16 + l16) * 32 + quad * 8];
#pragma unroll
    for (int i = 0; i < 4; ++i)
      b[i] = *(const bf16x8*)&Bs[(wn + i * 16 + l16) * 32 + quad * 8];

#pragma unroll
    for (int mi = 0; mi < 4; ++mi)
#pragma unroll
      for (int ni = 0; ni < 4; ++ni)
        acc[mi][ni] = __builtin_amdgcn_mfma_f32_16x16x32_bf16(
            a[mi], b[ni], acc[mi][ni], 0, 0, 0);
    __syncthreads();
  }

  const int which = n0 >> 10;  // 0=Q 1=K 2=V (block-uniform)
  const float* bias = which == 0 ? bq : which == 1 ? bk : bv;
  unsigned short* Out = which == 0 ? Qo : which == 1 ? Ko : Vo;

#pragma unroll
  for (int mi = 0; mi < 4; ++mi) {
#pragma unroll
    for (int ni = 0; ni < 4; ++ni) {
#pragma unroll
      for (int r = 0; r < 4; ++r) {
        const int m = m0 + wm + mi * 16 + quad * 4 + r;
        const int n = n0 + wn + ni * 16 + l16;
        const float val = acc[mi][ni][r] + bias[n & 1023];
        const int b = m >> 11, t = m & (T_ - 1);
        const int nl = n & 1023;
        const int h = nl >> 6, d = nl & (HD_ - 1);
        size_t idx;
        if (which == 2) {
          const int tp = (t & ~63) | (((t & 15) << 2) | ((t >> 4) & 3));
          idx = ((size_t)(b * H_ + h) * HD_ + d) * T_ + tp;
        } else {
          idx = ((size_t)(b * H_ + h) * T_ + t) * HD_ + d;
        }
        Out[idx] = f2b(val);
      }
    }
  }
}

// --------------------------- output GEMM (fp32) ----------------------------

__global__ __launch_bounds__(256, 2)
void gemm_out(const unsigned short* __restrict__ A,
              const unsigned short* __restrict__ Bt,
              const float* __restrict__ bias,
              float* __restrict__ Cout, int N, int K) {
  __shared__ unsigned short As[128 * 32];
  __shared__ unsigned short Bs[128 * 32];

  const int tid = threadIdx.x;
  const int wave = tid >> 6, lane = tid & 63;
  const int quad = lane >> 4, l16 = lane & 15;
  const int m0 = blockIdx.y * 128, n0 = blockIdx.x * 128;
  const int wm = (wave >> 1) * 64, wn = (wave & 1) * 64;

  const int c0 = wave * 2, c1 = c0 + 1;
  const int r0 = c0 * 16 + (lane >> 2);
  const int r1 = r0 + 16;
  const int kb = (lane & 3) * 8;

  const unsigned short* Ag0 = A + (size_t)(m0 + r0) * K + kb;
  const unsigned short* Ag1 = A + (size_t)(m0 + r1) * K + kb;
  const unsigned short* Bg0 = Bt + (size_t)(n0 + r0) * K + kb;
  const unsigned short* Bg1 = Bt + (size_t)(n0 + r1) * K + kb;

  floatx4 acc[4][4] = {};

  for (int kt = 0; kt < K; kt += 32) {
    async_ld16(Ag0 + kt, &As[c0 * 512]);
    async_ld16(Ag1 + kt, &As[c1 * 512]);
    async_ld16(Bg0 + kt, &Bs[c0 * 512]);
    async_ld16(Bg1 + kt, &Bs[c1 * 512]);
    __syncthreads();

    bf16x8 a[4], b[4];
#pragma unroll
    for (int i = 0; i < 4; ++i)
      a[i] = *(const bf16x8*)&As[(wm + i * 16 + l16) * 32 + quad * 8];
#pragma unroll
    for (int i = 0; i < 4; ++i)
      b[i] = *(const bf16x8*)&Bs[(wn + i * 16 + l16) * 32 + quad * 8];

#pragma unroll
    for (int mi = 0; mi < 4; ++mi)
#pragma unroll
      for (int ni = 0; ni < 4; ++ni)
        acc[mi][ni] = __builtin_amdgcn_mfma_f32_16x16x32_bf16(
            a[mi], b[ni], acc[mi][ni], 0, 0, 0);
    __syncthreads();
  }

#pragma unroll
  for (int mi = 0; mi < 4; ++mi)
#pragma unroll
    for (int ni = 0; ni < 4; ++ni)
#pragma unroll
      for (int r = 0; r < 4; ++r) {
        const int m = m0 + wm + mi * 16 + quad * 4 + r;
        const int n = n0 + wn + ni * 16 + l16;
        Cout[(size_t)m * N + n] = acc[mi][ni][r] + bias[n];
      }
}

// --------------------------- flash attention -------------------------------
// 1D grid 4096, 1-wave blocks. Each wave runs TWO 16-row q-tiles (i, 127-i):
// chunks(i)+chunks(127-i) = 33 uniformly -> zero occupancy tail.
// XCD swizzle: id&7 = xcd, 8 bh per XCD (K/V L2-resident).
// Fixed-offset softmax p = exp2(s*SL - CB) via raw v_exp_f32; l via ones-B
// MFMA. P C-layout -> A-frag through per-wave LDS (key-permuted V).

#define PSTR 72

template <bool MASKED>
__device__ __forceinline__ void attn_chunk16(
    int kbse, int qw, int quad, int l16,
    const unsigned short* __restrict__ Kb,
    const unsigned short* __restrict__ Vb,
    const bf16x8 (&aq)[2], floatx4 (&o)[4], floatx4 &lacc,
    unsigned short* __restrict__ pw, bf16x8 vones) {
  // K fragments (4 key tiles of 16)
  bf16x8 kf0[4], kf1[4];
#pragma unroll
  for (int j = 0; j < 4; ++j) {
    const unsigned short* kp = Kb + (size_t)(kbse + j * 16 + l16) * HD_ + quad * 8;
    kf0[j] = *(const bf16x8*)kp;
    kf1[j] = *(const bf16x8*)(kp + 32);
  }
  // QK^T (8 MFMA)
  floatx4 s[4] = {};
#pragma unroll
  for (int j = 0; j < 4; ++j) {
    s[j] = __builtin_amdgcn_mfma_f32_16x16x32_bf16(aq[0], kf0[j], s[j], 0, 0, 0);
    s[j] = __builtin_amdgcn_mfma_f32_16x16x32_bf16(aq[1], kf1[j], s[j], 0, 0, 0);
  }
  // V fragments (permuted layout, 16B contiguous)
  bf16x8 vf0[4], vf1[4];
#pragma unroll
  for (int d4 = 0; d4 < 4; ++d4) {
    const unsigned short* vp = Vb + (size_t)(d4 * 16 + l16) * T_ + kbse + quad * 8;
    vf0[d4] = *(const bf16x8*)vp;
    vf1[d4] = *(const bf16x8*)(vp + 32);
  }
  // fixed-offset softmax (pure per-lane) + P pack to LDS
  const float SL = 0.125f * 1.44269504f;
  const float CB = 8.0f * 1.44269504f;
#pragma unroll
  for (int r = 0; r < 4; ++r) {
    float v0 = s[0][r], v1 = s[1][r], v2 = s[2][r], v3 = s[3][r];
    if (MASKED) {
      const int qrow = qw + quad * 4 + r;
      if (kbse + l16 > qrow)      v0 = -1e30f;
      if (kbse + 16 + l16 > qrow) v1 = -1e30f;
      if (kbse + 32 + l16 > qrow) v2 = -1e30f;
      if (kbse + 48 + l16 > qrow) v3 = -1e30f;
    }
    const float p0 = fast_exp2(__builtin_fmaf(v0, SL, -CB));
    const float p1 = fast_exp2(__builtin_fmaf(v1, SL, -CB));
    const float p2 = fast_exp2(__builtin_fmaf(v2, SL, -CB));
    const float p3 = fast_exp2(__builtin_fmaf(v3, SL, -CB));
    // trunc-bf16 pack: one v_perm per pair; key l16+16i -> slot 4*l16+i
    uint2 pk;
    pk.x = __builtin_amdgcn_perm(__float_as_uint(p1), __float_as_uint(p0), 0x07060302u);
    pk.y = __builtin_amdgcn_perm(__float_as_uint(p3), __float_as_uint(p2), 0x07060302u);
    *(uint2*)&pw[(quad * 4 + r) * PSTR + 4 * l16] = pk;
  }
  // P (A-frag) x V ; row-sum via ones-B MFMA (12 MFMA)
  const bf16x8 pf0 = *(const bf16x8*)&pw[l16 * PSTR + quad * 8];
  const bf16x8 pf1 = *(const bf16x8*)&pw[l16 * PSTR + 32 + quad * 8];
  lacc = __builtin_amdgcn_mfma_f32_16x16x32_bf16(pf0, vones, lacc, 0, 0, 0);
  lacc = __builtin_amdgcn_mfma_f32_16x16x32_bf16(pf1, vones, lacc, 0, 0, 0);
#pragma unroll
  for (int d4 = 0; d4 < 4; ++d4) {
    o[d4] = __builtin_amdgcn_mfma_f32_16x16x32_bf16(pf0, vf0[d4], o[d4], 0, 0, 0);
    o[d4] = __builtin_amdgcn_mfma_f32_16x16x32_bf16(pf1, vf1[d4], o[d4], 0, 0, 0);
  }
}

__device__ __forceinline__ void attn_pass(
    int qw, int bh, int quad, int l16,
    const unsigned short* __restrict__ Qb,
    const unsigned short* __restrict__ Kb,
    const unsigned short* __restrict__ Vb,
    unsigned short* __restrict__ O,
    unsigned short* __restrict__ pw, bf16x8 vones) {
  bf16x8 aq[2];
  {
    const unsigned short* qp = Qb + (size_t)(qw + l16) * HD_ + quad * 8;
    aq[0] = *(const bf16x8*)qp;
    aq[1] = *(const bf16x8*)(qp + 32);
  }
  floatx4 o[4] = {};
  floatx4 lacc = {};

  const int nfull = qw >> 6;
  for (int kc = 0; kc < nfull; ++kc)
    attn_chunk16<false>(kc * 64, qw, quad, l16, Kb, Vb, aq, o, lacc, pw, vones);
  attn_chunk16<true>(nfull * 64, qw, quad, l16, Kb, Vb, aq, o, lacc, pw, vones);

  const int b = bh >> 4, h = bh & 15;
#pragma unroll
  for (int r = 0; r < 4; ++r) {
    const float inv = 1.0f / lacc[r];  // lane's lacc[r] = rowsum(quad*4+r)
    const int t = qw + quad * 4 + r;
    unsigned short* orow = O + (size_t)(b * T_ + t) * D_ + h * HD_;
    orow[l16]      = f2b(o[0][r] * inv);
    orow[16 + l16] = f2b(o[1][r] * inv);
    orow[32 + l16] = f2b(o[2][r] * inv);
    orow[48 + l16] = f2b(o[3][r] * inv);
  }
}

__global__ __launch_bounds__(64)
void attn_kernel(const unsigned short* __restrict__ Q,
                 const unsigned short* __restrict__ K,
                 const unsigned short* __restrict__ Vp,
                 unsigned short* __restrict__ O) {
  __shared__ unsigned short Pl[16 * PSTR];  // 2.25 KB, single wave

  // XCD swizzle (id&7 = xcd). slot>>6 = local bh (8 per XCD); slot&63 = pair.
  const int id = blockIdx.x;
  const int slot = id >> 3;
  const int bh = ((id & 7) << 3) | (slot >> 6);
  const int i = slot & 63;            // pair index: tiles (i, 127-i)
  const int qa = i * 16;              // small tile
  const int qb = (127 - i) * 16;      // big tile;  chunks(qa)+chunks(qb)=33

  const int lane = threadIdx.x & 63;
  const int quad = lane >> 4, l16 = lane & 15;

  const unsigned short* Qb = Q + (size_t)bh * T_ * HD_;
  const unsigned short* Kb = K + (size_t)bh * T_ * HD_;
  const unsigned short* Vb = Vp + (size_t)bh * HD_ * T_;

  union { unsigned short u[8]; bf16x8 v; } ones;
#pragma unroll
  for (int j = 0; j < 8; ++j) ones.u[j] = 0x3F80;  // bf16 1.0

  attn_pass(qb, bh, quad, l16, Qb, Kb, Vb, O, Pl, ones.v);
  attn_pass(qa, bh, quad, l16, Qb, Kb, Vb, O, Pl, ones.v);
}

// --------------------------- launcher --------------------------------------

extern "C" void kernel_launch(void* const* d_in, const int* in_sizes, int n_in,
                              void* d_out, int out_size, void* d_ws, size_t ws_size,
                              hipStream_t stream) {
  const float* x  = (const float*)d_in[0];
  const float* Wq = (const float*)d_in[1];
  const float* bq = (const float*)d_in[2];
  const float* Wk = (const float*)d_in[3];
  const float* bk = (const float*)d_in[4];
  const float* Wv = (const float*)d_in[5];
  const float* bv = (const float*)d_in[6];
  const float* Wo = (const float*)d_in[7];
  const float* bo = (const float*)d_in[8];
  float* out = (float*)d_out;

  char* ws = (char*)d_ws;
  const size_t MB = 1u << 20;
  unsigned short* xb  = (unsigned short*)(ws);              // 16 MB x bf16
  unsigned short* Wqt = (unsigned short*)(ws + 16 * MB);    // 2 MB (Wq^T)
  unsigned short* Wkt = (unsigned short*)(ws + 18 * MB);    // 2 MB (Wk^T) contiguous after Wqt
  unsigned short* Wvt = (unsigned short*)(ws + 20 * MB);    // 2 MB (Wv^T) contiguous after Wkt
  unsigned short* Wot = (unsigned short*)(ws + 22 * MB);    // 2 MB (Wo^T)
  unsigned short* Qb  = (unsigned short*)(ws + 24 * MB);    // 16 MB
  unsigned short* Kb  = (unsigned short*)(ws + 40 * MB);    // 16 MB
  unsigned short* Vtb = (unsigned short*)(ws + 56 * MB);    // 16 MB
  unsigned short* Ob  = xb;  // attn output aliases xb

  cast_fp32_to_bf16<<<dim3(M_ * D_ / 1024), dim3(256), 0, stream>>>(x, xb, M_ * D_);
  transpose_cast<<<dim3(32, 32, 4), dim3(32, 8), 0, stream>>>(
      Wq, Wk, Wv, Wo, Wqt, Wkt, Wvt, Wot);

  gemm_qkv<<<dim3(24, M_ / 128), dim3(256), 0, stream>>>(
      xb, Wqt, bq, bk, bv, Qb, Kb, Vtb);

  attn_kernel<<<dim3(4096), dim3(64), 0, stream>>>(Qb, Kb, Vtb, Ob);

  gemm_out<<<dim3(D_ / 128, M_ / 128), dim3(256), 0, stream>>>(
      Ob, Wot, bo, out, D_, D_);
}

// Round 8
// 341.023 us; speedup vs baseline: 1.3751x; 1.3751x over previous
//
#include <hip/hip_runtime.h>

// ---------------------------------------------------------------------------
// Causal self-attention, B=4 T=2048 D=1024 H=16 HD=64, fp32 in/out.
// cast x->bf16 ; transpose-cast W ; fused QKV GEMM (N=3072) ;
// flash attention (causal, fixed-offset softmax) ; O GEMM.
// MFMA v_mfma_f32_16x16x32_bf16, HW-verified layouts:
//   A/Bt frag: lane reads row (lane&15), k = (lane>>4)*8 .. +7 (16B contig)
//   C/D:       col = lane&15, row = (lane>>4)*4 + reg
// R8: back to R6's 32-row/wave chunk body (best attn: 161us) + fast exp2.
// Packaging fix: 4-wave workgroups (single-wave blocks cap at ~8 wg/CU ->
// 25% occ, measured R6/R7). 1024 blocks = 4/CU; waves take consecutive
// tiles {4k..4k+3} (intra-block ~uniform); the 4 blocks sharing a CU slot
// get complementary k {v,15-v,v+4,11-v} (cost sum 68 = const); XCD swizzle.
// ---------------------------------------------------------------------------

#define B_  4
#define T_  2048
#define D_  1024
#define H_  16
#define HD_ 64
#define M_  (B_ * T_)   // 8192 rows

typedef __bf16 bf16x8 __attribute__((ext_vector_type(8)));
typedef float  floatx4 __attribute__((ext_vector_type(4)));

__device__ __forceinline__ unsigned short f2b(float f) {
  unsigned int u = __float_as_uint(f);
  unsigned int r = (u + 0x7fffu + ((u >> 16) & 1u)) >> 16;
  return (unsigned short)r;
}

__device__ __forceinline__ float fast_exp2(float x) {
#if __has_builtin(__builtin_amdgcn_exp2f)
  return __builtin_amdgcn_exp2f(x);   // raw v_exp_f32
#else
  return exp2f(x);
#endif
}

__device__ __forceinline__ void async_ld16(const void* g, void* l) {
  __builtin_amdgcn_global_load_lds(
      (const __attribute__((address_space(1))) void*)g,
      (__attribute__((address_space(3))) void*)l, 16, 0, 0);
}

// --------------------------- prep kernels ----------------------------------

__global__ void cast_fp32_to_bf16(const float* __restrict__ in,
                                  unsigned short* __restrict__ out, int n) {
  int i = (blockIdx.x * 256 + threadIdx.x) * 4;
  if (i >= n) return;
  float4 v = *(const float4*)(in + i);
  ushort4 o;
  o.x = f2b(v.x); o.y = f2b(v.y); o.z = f2b(v.z); o.w = f2b(v.w);
  *(ushort4*)(out + i) = o;
}

__global__ void transpose_cast(const float* __restrict__ W0, const float* __restrict__ W1,
                               const float* __restrict__ W2, const float* __restrict__ W3,
                               unsigned short* __restrict__ O0, unsigned short* __restrict__ O1,
                               unsigned short* __restrict__ O2, unsigned short* __restrict__ O3) {
  __shared__ float tile[32][33];
  int z = blockIdx.z;
  const float* W = z == 0 ? W0 : z == 1 ? W1 : z == 2 ? W2 : W3;
  unsigned short* O = z == 0 ? O0 : z == 1 ? O1 : z == 2 ? O2 : O3;
  int n0 = blockIdx.x * 32, k0 = blockIdx.y * 32;
  int tx = threadIdx.x, ty = threadIdx.y;
#pragma unroll
  for (int i = 0; i < 4; ++i)
    tile[ty + i * 8][tx] = W[(size_t)(k0 + ty + i * 8) * D_ + n0 + tx];
  __syncthreads();
#pragma unroll
  for (int i = 0; i < 4; ++i)
    O[(size_t)(n0 + ty + i * 8) * D_ + k0 + tx] = f2b(tile[tx][ty + i * 8]);
}

// --------------------------- fused QKV GEMM --------------------------------
// A [8192][1024] bf16, Wt [3072][1024] bf16 (Wq^T|Wk^T|Wv^T contiguous).
// Q,K out: bf16 [B][H][T][HD]; V out: bf16 [B][H][HD][Tp] key-permuted.

__global__ __launch_bounds__(256, 2)
void gemm_qkv(const unsigned short* __restrict__ A,
              const unsigned short* __restrict__ Wt,
              const float* __restrict__ bq, const float* __restrict__ bk,
              const float* __restrict__ bv,
              unsigned short* __restrict__ Qo, unsigned short* __restrict__ Ko,
              unsigned short* __restrict__ Vo) {
  __shared__ unsigned short As[128 * 32];
  __shared__ unsigned short Bs[128 * 32];
  const int K = D_;

  const int tid = threadIdx.x;
  const int wave = tid >> 6, lane = tid & 63;
  const int quad = lane >> 4, l16 = lane & 15;
  const int m0 = blockIdx.y * 128, n0 = blockIdx.x * 128;
  const int wm = (wave >> 1) * 64, wn = (wave & 1) * 64;

  const int c0 = wave * 2, c1 = c0 + 1;
  const int r0 = c0 * 16 + (lane >> 2);
  const int r1 = r0 + 16;
  const int kb = (lane & 3) * 8;

  const unsigned short* Ag0 = A + (size_t)(m0 + r0) * K + kb;
  const unsigned short* Ag1 = A + (size_t)(m0 + r1) * K + kb;
  const unsigned short* Bg0 = Wt + (size_t)(n0 + r0) * K + kb;
  const unsigned short* Bg1 = Wt + (size_t)(n0 + r1) * K + kb;

  floatx4 acc[4][4] = {};

  for (int kt = 0; kt < K; kt += 32) {
    async_ld16(Ag0 + kt, &As[c0 * 512]);
    async_ld16(Ag1 + kt, &As[c1 * 512]);
    async_ld16(Bg0 + kt, &Bs[c0 * 512]);
    async_ld16(Bg1 + kt, &Bs[c1 * 512]);
    __syncthreads();

    bf16x8 a[4], b[4];
#pragma unroll
    for (int i = 0; i < 4; ++i)
      a[i] = *(const bf16x8*)&As[(wm + i * 16 + l16) * 32 + quad * 8];
#pragma unroll
    for (int i = 0; i < 4; ++i)
      b[i] = *(const bf16x8*)&Bs[(wn + i * 16 + l16) * 32 + quad * 8];

#pragma unroll
    for (int mi = 0; mi < 4; ++mi)
#pragma unroll
      for (int ni = 0; ni < 4; ++ni)
        acc[mi][ni] = __builtin_amdgcn_mfma_f32_16x16x32_bf16(
            a[mi], b[ni], acc[mi][ni], 0, 0, 0);
    __syncthreads();
  }

  const int which = n0 >> 10;  // 0=Q 1=K 2=V (block-uniform)
  const float* bias = which == 0 ? bq : which == 1 ? bk : bv;
  unsigned short* Out = which == 0 ? Qo : which == 1 ? Ko : Vo;

#pragma unroll
  for (int mi = 0; mi < 4; ++mi) {
#pragma unroll
    for (int ni = 0; ni < 4; ++ni) {
#pragma unroll
      for (int r = 0; r < 4; ++r) {
        const int m = m0 + wm + mi * 16 + quad * 4 + r;
        const int n = n0 + wn + ni * 16 + l16;
        const float val = acc[mi][ni][r] + bias[n & 1023];
        const int b = m >> 11, t = m & (T_ - 1);
        const int nl = n & 1023;
        const int h = nl >> 6, d = nl & (HD_ - 1);
        size_t idx;
        if (which == 2) {
          const int tp = (t & ~63) | (((t & 15) << 2) | ((t >> 4) & 3));
          idx = ((size_t)(b * H_ + h) * HD_ + d) * T_ + tp;
        } else {
          idx = ((size_t)(b * H_ + h) * T_ + t) * HD_ + d;
        }
        Out[idx] = f2b(val);
      }
    }
  }
}

// --------------------------- output GEMM (fp32) ----------------------------

__global__ __launch_bounds__(256, 2)
void gemm_out(const unsigned short* __restrict__ A,
              const unsigned short* __restrict__ Bt,
              const float* __restrict__ bias,
              float* __restrict__ Cout, int N, int K) {
  __shared__ unsigned short As[128 * 32];
  __shared__ unsigned short Bs[128 * 32];

  const int tid = threadIdx.x;
  const int wave = tid >> 6, lane = tid & 63;
  const int quad = lane >> 4, l16 = lane & 15;
  const int m0 = blockIdx.y * 128, n0 = blockIdx.x * 128;
  const int wm = (wave >> 1) * 64, wn = (wave & 1) * 64;

  const int c0 = wave * 2, c1 = c0 + 1;
  const int r0 = c0 * 16 + (lane >> 2);
  const int r1 = r0 + 16;
  const int kb = (lane & 3) * 8;

  const unsigned short* Ag0 = A + (size_t)(m0 + r0) * K + kb;
  const unsigned short* Ag1 = A + (size_t)(m0 + r1) * K + kb;
  const unsigned short* Bg0 = Bt + (size_t)(n0 + r0) * K + kb;
  const unsigned short* Bg1 = Bt + (size_t)(n0 + r1) * K + kb;

  floatx4 acc[4][4] = {};

  for (int kt = 0; kt < K; kt += 32) {
    async_ld16(Ag0 + kt, &As[c0 * 512]);
    async_ld16(Ag1 + kt, &As[c1 * 512]);
    async_ld16(Bg0 + kt, &Bs[c0 * 512]);
    async_ld16(Bg1 + kt, &Bs[c1 * 512]);
    __syncthreads();

    bf16x8 a[4], b[4];
#pragma unroll
    for (int i = 0; i < 4; ++i)
      a[i] = *(const bf16x8*)&As[(wm + i * 16 + l16) * 32 + quad * 8];
#pragma unroll
    for (int i = 0; i < 4; ++i)
      b[i] = *(const bf16x8*)&Bs[(wn + i * 16 + l16) * 32 + quad * 8];

#pragma unroll
    for (int mi = 0; mi < 4; ++mi)
#pragma unroll
      for (int ni = 0; ni < 4; ++ni)
        acc[mi][ni] = __builtin_amdgcn_mfma_f32_16x16x32_bf16(
            a[mi], b[ni], acc[mi][ni], 0, 0, 0);
    __syncthreads();
  }

#pragma unroll
  for (int mi = 0; mi < 4; ++mi)
#pragma unroll
    for (int ni = 0; ni < 4; ++ni)
#pragma unroll
      for (int r = 0; r < 4; ++r) {
        const int m = m0 + wm + mi * 16 + quad * 4 + r;
        const int n = n0 + wn + ni * 16 + l16;
        Cout[(size_t)m * N + n] = acc[mi][ni][r] + bias[n];
      }
}

// --------------------------- flash attention -------------------------------
// 1024 blocks x 4 waves (no __syncthreads; waves independent). Wave w of
// block handles 32-row q-tile (4k+w). Decode gives: same-bh blocks on one
// XCD; intra-block tiles consecutive (~uniform cost); the 4 blocks sharing
// a CU slot (b&255) have complementary k -> per-CU cost constant.
// Per 64-key chunk: QK -> (V loads + next-K prefetch) -> softmax -> PV.
// Fixed-offset softmax p = exp2(s*SL - CB); l via ones-B MFMA.

#define PSTR 72

template <bool MASKED, bool PREFETCH>
__device__ __forceinline__ void attn_chunk(
    int kbse, int qw, int quad, int l16,
    const unsigned short* __restrict__ Kb,
    const unsigned short* __restrict__ Vb,
    const bf16x8 (&aq)[2][2], floatx4 (&o)[2][4], floatx4 (&lacc)[2],
    bf16x8 (&kf0)[4], bf16x8 (&kf1)[4],
    unsigned short* __restrict__ pl0, unsigned short* __restrict__ pl1,
    bf16x8 vones) {
  // ---- QK^T from current K fragments ----
  floatx4 s[2][4] = {};
#pragma unroll
  for (int qt = 0; qt < 2; ++qt)
#pragma unroll
    for (int j = 0; j < 4; ++j) {
      s[qt][j] = __builtin_amdgcn_mfma_f32_16x16x32_bf16(aq[qt][0], kf0[j], s[qt][j], 0, 0, 0);
      s[qt][j] = __builtin_amdgcn_mfma_f32_16x16x32_bf16(aq[qt][1], kf1[j], s[qt][j], 0, 0, 0);
    }

  // ---- issue V loads + next-chunk K prefetch (hide under softmax) ----
  bf16x8 vf0[4], vf1[4];
#pragma unroll
  for (int d4 = 0; d4 < 4; ++d4) {
    const unsigned short* vp = Vb + (size_t)(d4 * 16 + l16) * T_ + kbse;
    vf0[d4] = *(const bf16x8*)(vp + quad * 8);
    vf1[d4] = *(const bf16x8*)(vp + 32 + quad * 8);
  }
  bf16x8 kn0[4], kn1[4];
  if (PREFETCH) {
#pragma unroll
    for (int j = 0; j < 4; ++j) {
      const unsigned short* kp = Kb + (size_t)(kbse + 64 + j * 16 + l16) * HD_;
      kn0[j] = *(const bf16x8*)(kp + quad * 8);
      kn1[j] = *(const bf16x8*)(kp + 32 + quad * 8);
    }
  }

  // ---- fixed-offset softmax (per-lane only) + P pack to LDS ----
  const float SL = 0.125f * 1.44269504f;
  const float CB = 8.0f * 1.44269504f;
#pragma unroll
  for (int qt = 0; qt < 2; ++qt) {
    unsigned short* pw = qt ? pl1 : pl0;
#pragma unroll
    for (int r = 0; r < 4; ++r) {
      float v0 = s[qt][0][r], v1 = s[qt][1][r], v2 = s[qt][2][r], v3 = s[qt][3][r];
      if (MASKED) {
        const int qrow = qw + qt * 16 + quad * 4 + r;
        if (kbse + l16 > qrow)      v0 = -1e30f;
        if (kbse + 16 + l16 > qrow) v1 = -1e30f;
        if (kbse + 32 + l16 > qrow) v2 = -1e30f;
        if (kbse + 48 + l16 > qrow) v3 = -1e30f;
      }
      const float p0 = fast_exp2(__builtin_fmaf(v0, SL, -CB));
      const float p1 = fast_exp2(__builtin_fmaf(v1, SL, -CB));
      const float p2 = fast_exp2(__builtin_fmaf(v2, SL, -CB));
      const float p3 = fast_exp2(__builtin_fmaf(v3, SL, -CB));
      // trunc-bf16 pack: one v_perm per pair; key l16+16i -> slot 4*l16+i
      uint2 pk;
      pk.x = __builtin_amdgcn_perm(__float_as_uint(p1), __float_as_uint(p0), 0x07060302u);
      pk.y = __builtin_amdgcn_perm(__float_as_uint(p3), __float_as_uint(p2), 0x07060302u);
      *(uint2*)&pw[(quad * 4 + r) * PSTR + 4 * l16] = pk;
    }
  }

  // ---- P (A-frag) x V ; row-sum via ones-B MFMA ----
#pragma unroll
  for (int qt = 0; qt < 2; ++qt) {
    const unsigned short* pw = qt ? pl1 : pl0;
    const bf16x8 pf0 = *(const bf16x8*)&pw[l16 * PSTR + quad * 8];
    const bf16x8 pf1 = *(const bf16x8*)&pw[l16 * PSTR + 32 + quad * 8];
    lacc[qt] = __builtin_amdgcn_mfma_f32_16x16x32_bf16(pf0, vones, lacc[qt], 0, 0, 0);
    lacc[qt] = __builtin_amdgcn_mfma_f32_16x16x32_bf16(pf1, vones, lacc[qt], 0, 0, 0);
#pragma unroll
    for (int d4 = 0; d4 < 4; ++d4) {
      o[qt][d4] = __builtin_amdgcn_mfma_f32_16x16x32_bf16(pf0, vf0[d4], o[qt][d4], 0, 0, 0);
      o[qt][d4] = __builtin_amdgcn_mfma_f32_16x16x32_bf16(pf1, vf1[d4], o[qt][d4], 0, 0, 0);
    }
  }

  // ---- rotate prefetched K into place ----
  if (PREFETCH) {
#pragma unroll
    for (int j = 0; j < 4; ++j) { kf0[j] = kn0[j]; kf1[j] = kn1[j]; }
  }
}

__global__ __launch_bounds__(256, 2)
void attn_kernel(const unsigned short* __restrict__ Q,
                 const unsigned short* __restrict__ K,
                 const unsigned short* __restrict__ Vp,
                 unsigned short* __restrict__ O) {
  __shared__ unsigned short Pl[4][2][16 * PSTR];  // 18 KB (per-wave regions)

  // decode: xcd = b&7 (8 bh each); CU slot = b&255; j = b>>8 picks the
  // complementary group k in {v, 15-v, v+4, 11-v} (cost sum 68 = const).
  const int bidx = blockIdx.x;
  const int xcd = bidx & 7;
  const int t = bidx >> 3;            // [0,128)
  const int j = t >> 5;               // [0,4)
  const int slot = t & 31;            // [0,32)
  const int bh_local = slot >> 2;     // [0,8)
  const int v = slot & 3;             // [0,4)
  const int k4 = (j == 0) ? v : (j == 1) ? 15 - v : (j == 2) ? v + 4 : 11 - v;
  const int bh = (xcd << 3) | bh_local;

  const int wave = threadIdx.x >> 6, lane = threadIdx.x & 63;
  const int quad = lane >> 4, l16 = lane & 15;
  const int tile = k4 * 4 + wave;     // [0,64)
  const int qw = tile * 32;

  const unsigned short* Qb = Q + (size_t)bh * T_ * HD_;
  const unsigned short* Kb = K + (size_t)bh * T_ * HD_;
  const unsigned short* Vb = Vp + (size_t)bh * HD_ * T_;

  bf16x8 aq[2][2];
#pragma unroll
  for (int qt = 0; qt < 2; ++qt) {
    const unsigned short* qp = Qb + (size_t)(qw + qt * 16 + l16) * HD_;
    aq[qt][0] = *(const bf16x8*)(qp + quad * 8);
    aq[qt][1] = *(const bf16x8*)(qp + 32 + quad * 8);
  }

  union { unsigned short u[8]; bf16x8 v8; } ones;
#pragma unroll
  for (int i = 0; i < 8; ++i) ones.u[i] = 0x3F80;  // bf16 1.0

  floatx4 o[2][4] = {};
  floatx4 lacc[2] = {};

  // initial K fragments (chunk 0)
  bf16x8 kf0[4], kf1[4];
#pragma unroll
  for (int jj = 0; jj < 4; ++jj) {
    const unsigned short* kp = Kb + (size_t)(jj * 16 + l16) * HD_;
    kf0[jj] = *(const bf16x8*)(kp + quad * 8);
    kf1[jj] = *(const bf16x8*)(kp + 32 + quad * 8);
  }

  const int nfull = qw >> 6;  // mask-free chunks; chunk nfull is diagonal
  for (int kc = 0; kc < nfull; ++kc)
    attn_chunk<false, true>(kc * 64, qw, quad, l16, Kb, Vb, aq, o, lacc,
                            kf0, kf1, &Pl[wave][0][0], &Pl[wave][1][0], ones.v8);
  attn_chunk<true, false>(nfull * 64, qw, quad, l16, Kb, Vb, aq, o, lacc,
                          kf0, kf1, &Pl[wave][0][0], &Pl[wave][1][0], ones.v8);

  const int b = bh >> 4, h = bh & 15;
#pragma unroll
  for (int qt = 0; qt < 2; ++qt) {
#pragma unroll
    for (int r = 0; r < 4; ++r) {
      const float inv = 1.0f / lacc[qt][r];  // every lane holds its row sum
      const int tt = qw + qt * 16 + quad * 4 + r;
      unsigned short* orow = O + (size_t)(b * T_ + tt) * D_ + h * HD_;
      orow[l16]      = f2b(o[qt][0][r] * inv);
      orow[16 + l16] = f2b(o[qt][1][r] * inv);
      orow[32 + l16] = f2b(o[qt][2][r] * inv);
      orow[48 + l16] = f2b(o[qt][3][r] * inv);
    }
  }
}

// --------------------------- launcher --------------------------------------

extern "C" void kernel_launch(void* const* d_in, const int* in_sizes, int n_in,
                              void* d_out, int out_size, void* d_ws, size_t ws_size,
                              hipStream_t stream) {
  const float* x  = (const float*)d_in[0];
  const float* Wq = (const float*)d_in[1];
  const float* bq = (const float*)d_in[2];
  const float* Wk = (const float*)d_in[3];
  const float* bk = (const float*)d_in[4];
  const float* Wv = (const float*)d_in[5];
  const float* bv = (const float*)d_in[6];
  const float* Wo = (const float*)d_in[7];
  const float* bo = (const float*)d_in[8];
  float* out = (float*)d_out;

  char* ws = (char*)d_ws;
  const size_t MB = 1u << 20;
  unsigned short* xb  = (unsigned short*)(ws);              // 16 MB x bf16
  unsigned short* Wqt = (unsigned short*)(ws + 16 * MB);    // 2 MB (Wq^T)
  unsigned short* Wkt = (unsigned short*)(ws + 18 * MB);    // 2 MB (Wk^T) contiguous after Wqt
  unsigned short* Wvt = (unsigned short*)(ws + 20 * MB);    // 2 MB (Wv^T) contiguous after Wkt
  unsigned short* Wot = (unsigned short*)(ws + 22 * MB);    // 2 MB (Wo^T)
  unsigned short* Qb  = (unsigned short*)(ws + 24 * MB);    // 16 MB
  unsigned short* Kb  = (unsigned short*)(ws + 40 * MB);    // 16 MB
  unsigned short* Vtb = (unsigned short*)(ws + 56 * MB);    // 16 MB
  unsigned short* Ob  = xb;  // attn output aliases xb

  cast_fp32_to_bf16<<<dim3(M_ * D_ / 1024), dim3(256), 0, stream>>>(x, xb, M_ * D_);
  transpose_cast<<<dim3(32, 32, 4), dim3(32, 8), 0, stream>>>(
      Wq, Wk, Wv, Wo, Wqt, Wkt, Wvt, Wot);

  gemm_qkv<<<dim3(24, M_ / 128), dim3(256), 0, stream>>>(
      xb, Wqt, bq, bk, bv, Qb, Kb, Vtb);

  attn_kernel<<<dim3(1024), dim3(256), 0, stream>>>(Qb, Kb, Vtb, Ob);

  gemm_out<<<dim3(D_ / 128, M_ / 128), dim3(256), 0, stream>>>(
      Ob, Wot, bo, out, D_, D_);
}